// Round 5
// baseline (1580.070 us; speedup 1.0000x reference)
//
#include <hip/hip_runtime.h>

#define T_TOK 8192
#define DIMX 1024
#define HID 4096
#define NE 8
#define TP (T_TOK * 2)   // 16384 routed (token,expert) pairs
#define PADR 128         // pad rows so partial tiles can over-read safely
#define BK 64

typedef unsigned short ushort_t;
typedef __attribute__((ext_vector_type(4))) float f32x4;
typedef __attribute__((ext_vector_type(8))) short bf16x8;
typedef __attribute__((ext_vector_type(8))) unsigned short u16x8;

__device__ __forceinline__ ushort_t f2bf(float f) {
    unsigned u = __float_as_uint(f);
    u += 0x7FFFu + ((u >> 16) & 1u);   // RNE
    return (ushort_t)(u >> 16);
}
__device__ __forceinline__ float b2f(ushort_t h) {
    return __uint_as_float(((unsigned)h) << 16);
}

// async global->LDS, 16B per lane. LDS dest is wave-uniform base + lane*16,
// so lds ptr MUST be base + lane*16 in-order (no padding allowed).
__device__ __forceinline__ void gload_lds16(const void* g, void* l) {
    __builtin_amdgcn_global_load_lds((const __attribute__((address_space(1))) void*)g,
                                     (__attribute__((address_space(3))) void*)l, 16, 0, 0);
}

__device__ __forceinline__ f32x4 mfma16(bf16x8 a, bf16x8 b, f32x4 c) {
    return __builtin_amdgcn_mfma_f32_16x16x32_bf16(a, b, c, 0, 0, 0);
}

// ---------------- routing ----------------

// one wave per token; logits in exact fp32 (no atomics — counts done in prefix)
__global__ __launch_bounds__(256) void router_kernel(
    const float* __restrict__ x, const float* __restrict__ rw, const float* __restrict__ rb,
    int* __restrict__ topk_idx, float* __restrict__ topk_w)
{
    __shared__ float s_rw[NE * DIMX];
    int tid = threadIdx.x;
    for (int i = tid * 4; i < NE * DIMX; i += 1024) {
        float4 v = *(const float4*)(rw + i);
        *(float4*)(s_rw + i) = v;
    }
    __syncthreads();
    int lane = tid & 63, wid = tid >> 6;
    int t = blockIdx.x * 4 + wid;
    const float* xr = x + (size_t)t * DIMX;
    float acc[NE];
#pragma unroll
    for (int e = 0; e < NE; e++) acc[e] = 0.f;
    for (int j = 0; j < DIMX; j += 64) {
        float xv = xr[j + lane];
#pragma unroll
        for (int e = 0; e < NE; e++) acc[e] += xv * s_rw[e * DIMX + j + lane];
    }
#pragma unroll
    for (int e = 0; e < NE; e++) {
#pragma unroll
        for (int off = 32; off > 0; off >>= 1) acc[e] += __shfl_xor(acc[e], off, 64);
    }
    if (lane == 0) {
        float v[NE];
#pragma unroll
        for (int e = 0; e < NE; e++) v[e] = acc[e] + rb[e];
        int i0 = 0; float b0 = v[0];
#pragma unroll
        for (int e = 1; e < NE; e++) if (v[e] > b0) { b0 = v[e]; i0 = e; }  // strict > : lowest idx on tie
        int i1 = -1; float b1v = -1e30f;
#pragma unroll
        for (int e = 0; e < NE; e++) if (e != i0 && v[e] > b1v) { b1v = v[e]; i1 = e; }
        float ex = __expf(b1v - b0);
        float inv = 1.f / (1.f + ex);
        topk_idx[t * 2]     = i0;  topk_idx[t * 2 + 1] = i1;
        topk_w[t * 2]       = inv; topk_w[t * 2 + 1]   = ex * inv;
    }
}

// single block: histogram of topk_idx -> counts, offsets; zero cursor
__global__ __launch_bounds__(256) void prefix_kernel(
    const int* __restrict__ topk_idx, int* __restrict__ counts,
    int* __restrict__ offsets, int* __restrict__ cursor)
{
    __shared__ int hist[NE * 256];
    int tid = threadIdx.x;
    int loc[NE];
#pragma unroll
    for (int e = 0; e < NE; e++) loc[e] = 0;
    for (int i = tid; i < TP; i += 256) loc[topk_idx[i]]++;
#pragma unroll
    for (int e = 0; e < NE; e++) hist[e * 256 + tid] = loc[e];
    __syncthreads();
    if (tid < NE) {
        int s = 0;
        for (int j = 0; j < 256; j++) s += hist[tid * 256 + j];
        counts[tid] = s;
        cursor[tid] = 0;
    }
    __syncthreads();
    if (tid == 0) {
        int s = 0;
        for (int e = 0; e < NE; e++) { offsets[e] = s; s += counts[e]; }
    }
}

// scatter + gather fused: one block per token, copy its row (bf16) to both slots
__global__ __launch_bounds__(256) void sg_kernel(
    const float* __restrict__ x, const int* __restrict__ topk_idx,
    const float* __restrict__ topk_w, const int* __restrict__ offsets,
    int* __restrict__ cursor, ushort_t* __restrict__ Xp,
    float* __restrict__ w_of, int* __restrict__ slot_of)
{
    __shared__ int s_pos[2];
    int t = blockIdx.x;
    if (threadIdx.x == 0) {
        int e0 = topk_idx[2 * t], e1 = topk_idx[2 * t + 1];
        int p0 = offsets[e0] + atomicAdd(&cursor[e0], 1);
        int p1 = offsets[e1] + atomicAdd(&cursor[e1], 1);
        s_pos[0] = p0; s_pos[1] = p1;
        w_of[p0] = topk_w[2 * t]; w_of[p1] = topk_w[2 * t + 1];
        slot_of[2 * t] = p0; slot_of[2 * t + 1] = p1;
    }
    __syncthreads();
    int p0 = s_pos[0], p1 = s_pos[1];
    int i = threadIdx.x;
    float4 v = ((const float4*)(x + (size_t)t * DIMX))[i];
    ushort4 o = make_ushort4(f2bf(v.x), f2bf(v.y), f2bf(v.z), f2bf(v.w));
    ((ushort4*)(Xp + (size_t)p0 * DIMX))[i] = o;
    ((ushort4*)(Xp + (size_t)p1 * DIMX))[i] = o;
}

// ---------------- dtype prep ----------------

// fused fp32->bf16 conversion for w1+w2, grid-stride, 16B stores
__global__ __launch_bounds__(256) void cvt_kernel(
    const float* __restrict__ w1, ushort_t* __restrict__ w1d,
    const float* __restrict__ w2, ushort_t* __restrict__ w2d)
{
    const int n8_w1 = NE * 2 * HID * DIMX / 8;
    const int n8_tot = n8_w1 + NE * DIMX * HID / 8;
    int stride = gridDim.x * 256;
    for (int i = blockIdx.x * 256 + threadIdx.x; i < n8_tot; i += stride) {
        const float* src; ushort_t* dst; int j;
        if (i < n8_w1) { src = w1; dst = w1d; j = i; }
        else           { src = w2; dst = w2d; j = i - n8_w1; }
        float4 a = ((const float4*)src)[j * 2];
        float4 b = ((const float4*)src)[j * 2 + 1];
        u16x8 o = { f2bf(a.x), f2bf(a.y), f2bf(a.z), f2bf(a.w),
                    f2bf(b.x), f2bf(b.y), f2bf(b.z), f2bf(b.w) };
        ((u16x8*)dst)[j] = o;
    }
}

// ---------------- fc1: H = silu(Xp W1a^T + b1a) * (Xp W1b^T + b1b) ----------------
// block: 128 rows x 64 hidden cols (both swiglu halves). 4 waves 2x2.
// XCD-affinity swizzle (e = wg&7) + banded mt/nt order (round-4, FETCH 586->216 MB).
// Round-5: double-buffered K-loop — prefetch tile ko+1 via global_load_lds
// BEFORE computing tile ko, so the barrier's vmcnt drain lands after ~a full
// compute phase instead of immediately after issue. Plain __syncthreads only.
__global__ __launch_bounds__(256, 2) void fc1_kernel(
    const ushort_t* __restrict__ Xp, const ushort_t* __restrict__ w1b,
    const float* __restrict__ b1,
    const int* __restrict__ counts, const int* __restrict__ offsets,
    ushort_t* __restrict__ H)
{
    // swizzled decode: wg -> (e, band, nt, mi)
    const int wg = blockIdx.x;
    const int e  = wg & 7;
    const int r  = wg >> 3;           // [0, 2048) per expert
    const int band = r >> 9;          // [0,4): mt-band of 8 tiles
    const int rem  = r & 511;
    const int nt   = rem >> 3;        // [0,64) nt outer
    const int mt   = band * 8 + (rem & 7);   // mt inner (band-local)

    const int cnt = counts[e];
    if (mt * 128 >= cnt) return;
    const int base = offsets[e] + mt * 128;
    int rows_valid = cnt - mt * 128; if (rows_valid > 128) rows_valid = 128;

    __shared__ ushort_t As[2 * 128 * BK];    // 32 KB (dbuf)
    __shared__ ushort_t Bs1[2 * 64 * BK];    // 16 KB (dbuf)
    __shared__ ushort_t Bs2[2 * 64 * BK];    // 16 KB (dbuf)

    const int tid = threadIdx.x, lane = tid & 63, wid = tid >> 6;
    const int wave_m = wid >> 1, wave_n = wid & 1;

    const ushort_t* Ag  = Xp + (size_t)base * DIMX;
    const ushort_t* B1g = w1b + ((size_t)e * 2 * HID + (size_t)nt * 64) * DIMX;
    const ushort_t* B2g = B1g + (size_t)HID * DIMX;

    // staging: XOR-swizzle chunk c' = c ^ (row&7) so frag ds_read_b128 is ~2-way (free)
    const ushort_t* agp[4]; int aoff[4];
#pragma unroll
    for (int i = 0; i < 4; i++) {
        int s = wid * 4 + i;
        int r2 = s * 8 + (lane >> 3);
        int c = (lane & 7) ^ (r2 & 7);
        agp[i] = Ag + (size_t)r2 * DIMX + c * 8;
        aoff[i] = s * 512 + lane * 8;
    }
    const ushort_t* bgp[4]; int boff[4];
#pragma unroll
    for (int i = 0; i < 2; i++) {
        int s = wid * 2 + i;
        int r2 = s * 8 + (lane >> 3);
        int c = (lane & 7) ^ (r2 & 7);
        bgp[i]     = B1g + (size_t)r2 * DIMX + c * 8;
        boff[i]     = s * 512 + lane * 8;
        bgp[2 + i] = B2g + (size_t)r2 * DIMX + c * 8;
        boff[2 + i] = s * 512 + lane * 8;
    }

#define FC1_STAGE(SEL) do {                                                   \
        _Pragma("unroll")                                                     \
        for (int i = 0; i < 4; i++) gload_lds16(agp[i], As + (SEL) * 8192 + aoff[i]); \
        gload_lds16(bgp[0], Bs1 + (SEL) * 4096 + boff[0]);                    \
        gload_lds16(bgp[1], Bs1 + (SEL) * 4096 + boff[1]);                    \
        gload_lds16(bgp[2], Bs2 + (SEL) * 4096 + boff[2]);                    \
        gload_lds16(bgp[3], Bs2 + (SEL) * 4096 + boff[3]);                    \
        _Pragma("unroll")                                                     \
        for (int i = 0; i < 4; i++) { agp[i] += BK; bgp[i] += BK; }           \
    } while (0)

    f32x4 acc1[4][2], acc2[4][2];
#pragma unroll
    for (int mf = 0; mf < 4; mf++)
#pragma unroll
        for (int nf = 0; nf < 2; nf++) {
            acc1[mf][nf] = (f32x4){0.f, 0.f, 0.f, 0.f};
            acc2[mf][nf] = (f32x4){0.f, 0.f, 0.f, 0.f};
        }

    const int q = lane >> 4, rA = lane & 15;
    FC1_STAGE(0);
    __syncthreads();

    for (int ko = 0; ko < DIMX / BK; ko++) {
        const int cur = ko & 1;
        if (ko + 1 < DIMX / BK) FC1_STAGE(cur ^ 1);   // prefetch next tile

        const ushort_t* Ac  = As  + cur * 8192;
        const ushort_t* B1c = Bs1 + cur * 4096;
        const ushort_t* B2c = Bs2 + cur * 4096;

        bf16x8 af[4][2], bf1[2][2], bf2[2][2];
#pragma unroll
        for (int mf = 0; mf < 4; mf++) {
            int r2 = wave_m * 64 + mf * 16 + rA;
            const ushort_t* rp = Ac + r2 * BK;
            af[mf][0] = *(const bf16x8*)(rp + ((q    ) ^ (r2 & 7)) * 8);
            af[mf][1] = *(const bf16x8*)(rp + ((q + 4) ^ (r2 & 7)) * 8);
        }
#pragma unroll
        for (int nf = 0; nf < 2; nf++) {
            int r2 = wave_n * 32 + nf * 16 + rA;
            const ushort_t* rp1 = B1c + r2 * BK;
            const ushort_t* rp2 = B2c + r2 * BK;
            bf1[nf][0] = *(const bf16x8*)(rp1 + ((q    ) ^ (r2 & 7)) * 8);
            bf1[nf][1] = *(const bf16x8*)(rp1 + ((q + 4) ^ (r2 & 7)) * 8);
            bf2[nf][0] = *(const bf16x8*)(rp2 + ((q    ) ^ (r2 & 7)) * 8);
            bf2[nf][1] = *(const bf16x8*)(rp2 + ((q + 4) ^ (r2 & 7)) * 8);
        }
#pragma unroll
        for (int mf = 0; mf < 4; mf++)
#pragma unroll
            for (int nf = 0; nf < 2; nf++) {
                acc1[mf][nf] = mfma16(af[mf][0], bf1[nf][0], acc1[mf][nf]);
                acc1[mf][nf] = mfma16(af[mf][1], bf1[nf][1], acc1[mf][nf]);
                acc2[mf][nf] = mfma16(af[mf][0], bf2[nf][0], acc2[mf][nf]);
                acc2[mf][nf] = mfma16(af[mf][1], bf2[nf][1], acc2[mf][nf]);
            }
        __syncthreads();   // drains prefetch (issued a full compute phase ago) + syncs buffers
    }

    // epilogue: C/D layout col=lane&15, row=(lane>>4)*4+reg
    const float* b1p = b1 + (size_t)e * 2 * HID + (size_t)nt * 64;
    const bool full = (rows_valid == 128);
#pragma unroll
    for (int mf = 0; mf < 4; mf++) {
#pragma unroll
        for (int nf = 0; nf < 2; nf++) {
            int col = wave_n * 32 + nf * 16 + rA;
            float bb1 = b1p[col];
            float bb2 = b1p[HID + col];
#pragma unroll
            for (int rr = 0; rr < 4; rr++) {
                int row = wave_m * 64 + mf * 16 + q * 4 + rr;
                if (full || row < rows_valid) {
                    float v1 = acc1[mf][nf][rr] + bb1;
                    float v2 = acc2[mf][nf][rr] + bb2;
                    float hv = v1 * v2 / (1.f + __expf(-v1));   // silu(v1)*v2
                    H[(size_t)(base + row) * HID + (size_t)nt * 64 + col] = f2bf(hv);
                }
            }
        }
    }
}

// ---------------- fc2: Os[pos] = w_of[pos] * (H[pos] W2^T + b2) ----------------
// block: 128 rows x 128 out cols. 4 waves 2x2. Expert->XCD affinity via wg&7;
// nt outer, mt fastest. Round-5: double-buffered K-loop (see fc1).
__global__ __launch_bounds__(256, 2) void fc2_kernel(
    const ushort_t* __restrict__ H, const ushort_t* __restrict__ w2b,
    const float* __restrict__ b2,
    const int* __restrict__ counts, const int* __restrict__ offsets,
    const float* __restrict__ w_of, ushort_t* __restrict__ Os)
{
    const int wg = blockIdx.x;
    const int e  = wg & 7;
    const int r  = wg >> 3;          // [0,256) per expert
    const int nt = r >> 5;           // [0,8) nt outer
    const int mt = r & 31;           // mt fastest

    const int cnt = counts[e];
    if (mt * 128 >= cnt) return;
    const int base = offsets[e] + mt * 128;
    int rows_valid = cnt - mt * 128; if (rows_valid > 128) rows_valid = 128;

    __shared__ ushort_t As[2 * 128 * BK];   // 32 KB (dbuf)
    __shared__ ushort_t Bs[2 * 128 * BK];   // 32 KB (dbuf)

    const int tid = threadIdx.x, lane = tid & 63, wid = tid >> 6;
    const int wave_m = wid >> 1, wave_n = wid & 1;

    const ushort_t* Ag = H + (size_t)base * HID;
    const ushort_t* Bg = w2b + ((size_t)e * DIMX + (size_t)nt * 128) * HID;

    const ushort_t* agp[4]; int aoff[4];
    const ushort_t* bgp[4];
#pragma unroll
    for (int i = 0; i < 4; i++) {
        int s = wid * 4 + i;
        int r2 = s * 8 + (lane >> 3);
        int c = (lane & 7) ^ (r2 & 7);
        agp[i] = Ag + (size_t)r2 * HID + c * 8;
        aoff[i] = s * 512 + lane * 8;
        bgp[i] = Bg + (size_t)r2 * HID + c * 8;
    }

#define FC2_STAGE(SEL) do {                                                   \
        _Pragma("unroll")                                                     \
        for (int i = 0; i < 4; i++) gload_lds16(agp[i], As + (SEL) * 8192 + aoff[i]); \
        _Pragma("unroll")                                                     \
        for (int i = 0; i < 4; i++) gload_lds16(bgp[i], Bs + (SEL) * 8192 + aoff[i]); \
        _Pragma("unroll")                                                     \
        for (int i = 0; i < 4; i++) { agp[i] += BK; bgp[i] += BK; }           \
    } while (0)

    f32x4 acc[4][4];
#pragma unroll
    for (int mf = 0; mf < 4; mf++)
#pragma unroll
        for (int nf = 0; nf < 4; nf++) acc[mf][nf] = (f32x4){0.f, 0.f, 0.f, 0.f};

    const int q = lane >> 4, rA = lane & 15;
    FC2_STAGE(0);
    __syncthreads();

    for (int ko = 0; ko < HID / BK; ko++) {
        const int cur = ko & 1;
        if (ko + 1 < HID / BK) FC2_STAGE(cur ^ 1);   // prefetch next tile

        const ushort_t* Ac = As + cur * 8192;
        const ushort_t* Bc = Bs + cur * 8192;

        bf16x8 af[4][2], bfr[4][2];
#pragma unroll
        for (int mf = 0; mf < 4; mf++) {
            int r2 = wave_m * 64 + mf * 16 + rA;
            const ushort_t* rp = Ac + r2 * BK;
            af[mf][0] = *(const bf16x8*)(rp + ((q    ) ^ (r2 & 7)) * 8);
            af[mf][1] = *(const bf16x8*)(rp + ((q + 4) ^ (r2 & 7)) * 8);
        }
#pragma unroll
        for (int nf = 0; nf < 4; nf++) {
            int r2 = wave_n * 64 + nf * 16 + rA;
            const ushort_t* rp = Bc + r2 * BK;
            bfr[nf][0] = *(const bf16x8*)(rp + ((q    ) ^ (r2 & 7)) * 8);
            bfr[nf][1] = *(const bf16x8*)(rp + ((q + 4) ^ (r2 & 7)) * 8);
        }
#pragma unroll
        for (int mf = 0; mf < 4; mf++)
#pragma unroll
            for (int nf = 0; nf < 4; nf++) {
                acc[mf][nf] = mfma16(af[mf][0], bfr[nf][0], acc[mf][nf]);
                acc[mf][nf] = mfma16(af[mf][1], bfr[nf][1], acc[mf][nf]);
            }
        __syncthreads();
    }

    const float* b2p = b2 + (size_t)e * DIMX + (size_t)nt * 128;
    const bool full = (rows_valid == 128);
#pragma unroll
    for (int mf = 0; mf < 4; mf++) {
#pragma unroll
        for (int rr = 0; rr < 4; rr++) {
            int row = wave_m * 64 + mf * 16 + q * 4 + rr;
            if (full || row < rows_valid) {
                float wv = w_of[base + row];
#pragma unroll
                for (int nf = 0; nf < 4; nf++) {
                    int col = wave_n * 64 + nf * 16 + rA;
                    float val = (acc[mf][nf][rr] + b2p[col]) * wv;
                    Os[(size_t)(base + row) * DIMX + (size_t)nt * 128 + col] = f2bf(val);
                }
            }
        }
    }
}

// ---------------- combine: out[t] = Os[slot0] + Os[slot1] (already weighted) ----------------
__global__ __launch_bounds__(256) void combine_kernel(
    const ushort_t* __restrict__ Os, const int* __restrict__ slot_of, float* __restrict__ out)
{
    int t = blockIdx.x;
    int p0 = slot_of[t * 2], p1 = slot_of[t * 2 + 1];
    int i = threadIdx.x;
    ushort4 a = ((const ushort4*)(Os + (size_t)p0 * DIMX))[i];
    ushort4 b = ((const ushort4*)(Os + (size_t)p1 * DIMX))[i];
    float4 o;
    o.x = b2f(a.x) + b2f(b.x);
    o.y = b2f(a.y) + b2f(b.y);
    o.z = b2f(a.z) + b2f(b.z);
    o.w = b2f(a.w) + b2f(b.w);
    ((float4*)(out + (size_t)t * DIMX))[i] = o;
}

// ---------------- launch ----------------

extern "C" void kernel_launch(void* const* d_in, const int* in_sizes, int n_in,
                              void* d_out, int out_size, void* d_ws, size_t ws_size,
                              hipStream_t stream) {
    (void)in_sizes; (void)n_in; (void)out_size; (void)ws_size;
    const float* x  = (const float*)d_in[0];
    const float* rw = (const float*)d_in[1];
    const float* rb = (const float*)d_in[2];
    const float* w1 = (const float*)d_in[3];
    const float* b1 = (const float*)d_in[4];
    const float* w2 = (const float*)d_in[5];
    const float* b2 = (const float*)d_in[6];
    float* out = (float*)d_out;

    // workspace layout (~357 MB). Os overlays Xp (dead after fc1).
    char* p = (char*)d_ws;
    ushort_t* w1b = (ushort_t*)p; p += (size_t)NE * 2 * HID * DIMX * 2;        // 128 MB
    ushort_t* w2b = (ushort_t*)p; p += (size_t)NE * DIMX * HID * 2;            //  64 MB
    ushort_t* Xp  = (ushort_t*)p; p += (size_t)(TP + PADR) * DIMX * 2;         //  33 MB
    ushort_t* Hb  = (ushort_t*)p; p += (size_t)(TP + PADR) * HID * 2;          // 132 MB
    int* ints     = (int*)p;      p += 24 * sizeof(int);
    int*   counts  = ints;
    int*   cursor  = ints + 8;
    int*   offsets = ints + 16;
    int*   topk_idx = (int*)p;   p += (size_t)TP * 4;
    float* topk_w   = (float*)p; p += (size_t)TP * 4;
    float* w_of     = (float*)p; p += (size_t)TP * 4;
    int*   slot_of  = (int*)p;   p += (size_t)TP * 4;
    ushort_t* Os = Xp;                  // 32 MB needed, 33 MB available

    router_kernel<<<T_TOK / 4, 256, 0, stream>>>(x, rw, rb, topk_idx, topk_w);
    prefix_kernel<<<1, 256, 0, stream>>>(topk_idx, counts, offsets, cursor);
    sg_kernel<<<T_TOK, 256, 0, stream>>>(x, topk_idx, topk_w, offsets, cursor,
                                         Xp, w_of, slot_of);
    cvt_kernel<<<2048, 256, 0, stream>>>(w1, w1b, w2, w2b);

    // fc1: merged single launch, 1-D swizzled grid: 8 e x 4 band x 64 nt x 8 mi
    fc1_kernel<<<NE * 32 * 64, 256, 0, stream>>>(Xp, w1b, b1, counts, offsets, Hb);
    // fc2: 1-D swizzled grid: 8 e x 8 nt x 32 mt
    fc2_kernel<<<NE * 8 * 32, 256, 0, stream>>>(Hb, w2b, b2, counts, offsets, w_of, Os);
    combine_kernel<<<T_TOK, 256, 0, stream>>>(Os, slot_of, out);
}